// Round 12
// baseline (650.952 us; speedup 1.0000x reference)
//
#include <hip/hip_runtime.h>
#include <hip/hip_bf16.h>

constexpr int NN = 100000;   // nodes
constexpr int NE = 1600000;  // edges
constexpr int NF = 64;       // input features
constexpr int NH = 16;       // hidden

constexpr int NPB  = 128;                      // nodes per bucket (dst>>7 / dst&127)
constexpr int LB   = 7;                        // log2(NPB)
constexpr int NBKT = (NN + NPB - 1) / NPB;     // 782 buckets
constexpr int CAP  = 2560;                     // per-bucket edge capacity (mean 2046, +11 sigma)
constexpr int TB   = 512;                      // fused-kernel block size
constexpr int CHUNK = 8192;                    // edges per bucket-role block
constexpr int NBF   = (NE + CHUNK - 1) / CHUNK;   // 196 bucket-role blocks / fragments
constexpr int NPG   = 2 * TB;                     // nodes per gemm-role block (2/thread)
constexpr int NBLK_K1 = (NN + NPG - 1) / NPG;     // 98 gemm-role blocks
constexpr int FD = NBKT + 1;                      // directory row stride (783)

// bucket-role LDS: srk 16K(u16) + lcnt 3.1K + fscan 3.1K + tscan 2K = 24.3 KB
constexpr int SMEM_BYTES = CHUNK * 2 + NBKT * 4 + FD * 4 + TB * 4;

__device__ __forceinline__ float bf16_to_f32(unsigned short u) {
    return __uint_as_float(((unsigned int)u) << 16);
}
__device__ __forceinline__ unsigned short f32_to_bf16(float f) {
    __hip_bfloat16 hb = __float2bfloat16(f);   // RNE
    return *reinterpret_cast<unsigned short*>(&hb);
}

// Fused front-end, 512 threads, 294-block grid ([bucket,bucket,gemm] pattern:
// 196 bucket-role + 98 gemm-role). GEMM role: 2 nodes per thread so each LDS
// weight read feeds 2x the FMAs (the LDS pipe is the shared critical path).
__global__ __launch_bounds__(TB)
void k_fused(const float* __restrict__ x,
             const float* __restrict__ Wl1,
             const float* __restrict__ Wr1,
             unsigned short* __restrict__ p,
             float* __restrict__ r,
             const int* __restrict__ ei, const float* __restrict__ As,
             const float* __restrict__ ws,
             unsigned int* __restrict__ gchunk, int* __restrict__ fdir)
{
    __shared__ __align__(16) char smem[SMEM_BYTES];
    int t    = blockIdx.x;
    int role = ((t % 3) == 2);                 // every 3rd block is gemm
    int rb   = role ? (t / 3) : (t - t / 3);
    int tid  = threadIdx.x;

    if (role) {
        // ---- GEMM role: nodes rb*1024 + tid, + 512 (2 per thread) ----
        float* sW = (float*)smem;              // Wl1 | Wr1 row-major [k][j]
        for (int i = tid; i < NF * NH; i += TB) {
            sW[i]           = Wl1[i];
            sW[NF * NH + i] = Wr1[i];
        }
        __syncthreads();

        int n0 = rb * NPG + tid;
        int n1 = n0 + TB;
        bool v0 = n0 < NN, v1 = n1 < NN;
        if (!v0) return;

        float aL0[NH], aR0[NH], aL1[NH], aR1[NH];
#pragma unroll
        for (int j = 0; j < NH; ++j) {
            aL0[j] = 0.f; aR0[j] = 0.f; aL1[j] = 0.f; aR1[j] = 0.f;
        }

        const float4* xr0 = reinterpret_cast<const float4*>(x + (size_t)n0 * NF);
        const float4* xr1 = reinterpret_cast<const float4*>(x + (size_t)(v1 ? n1 : n0) * NF);
#pragma unroll
        for (int k4 = 0; k4 < NF / 4; ++k4) {
            float4 va = xr0[k4];
            float4 vb = xr1[k4];
            float xa[4] = {va.x, va.y, va.z, va.w};
            float xb[4] = {vb.x, vb.y, vb.z, vb.w};
#pragma unroll
            for (int t2 = 0; t2 < 4; ++t2) {
                const float* wl = &sW[(k4 * 4 + t2) * NH];
                const float* wr = &sW[NF * NH + (k4 * 4 + t2) * NH];
#pragma unroll
                for (int j = 0; j < NH; ++j) {
                    float wlv = wl[j], wrv = wr[j];
                    aL0[j] = fmaf(xa[t2], wlv, aL0[j]);
                    aR0[j] = fmaf(xa[t2], wrv, aR0[j]);
                    aL1[j] = fmaf(xb[t2], wlv, aL1[j]);
                    aR1[j] = fmaf(xb[t2], wrv, aR1[j]);
                }
            }
        }

        // node 0 stores
        {
            unsigned int pu[8];
#pragma unroll
            for (int j2 = 0; j2 < 8; ++j2)
                pu[j2] = (unsigned int)f32_to_bf16(aL0[2*j2]) |
                         ((unsigned int)f32_to_bf16(aL0[2*j2+1]) << 16);
            uint4* pp = reinterpret_cast<uint4*>(p + (size_t)n0 * NH);
            pp[0] = make_uint4(pu[0], pu[1], pu[2], pu[3]);
            pp[1] = make_uint4(pu[4], pu[5], pu[6], pu[7]);
            float4* rp = reinterpret_cast<float4*>(r + (size_t)n0 * NH);
#pragma unroll
            for (int j4 = 0; j4 < NH / 4; ++j4)
                rp[j4] = make_float4(aR0[j4*4], aR0[j4*4+1], aR0[j4*4+2], aR0[j4*4+3]);
        }
        // node 1 stores
        if (v1) {
            unsigned int pu[8];
#pragma unroll
            for (int j2 = 0; j2 < 8; ++j2)
                pu[j2] = (unsigned int)f32_to_bf16(aL1[2*j2]) |
                         ((unsigned int)f32_to_bf16(aL1[2*j2+1]) << 16);
            uint4* pp = reinterpret_cast<uint4*>(p + (size_t)n1 * NH);
            pp[0] = make_uint4(pu[0], pu[1], pu[2], pu[3]);
            pp[1] = make_uint4(pu[4], pu[5], pu[6], pu[7]);
            float4* rp = reinterpret_cast<float4*>(r + (size_t)n1 * NH);
#pragma unroll
            for (int j4 = 0; j4 < NH / 4; ++j4)
                rp[j4] = make_float4(aR1[j4*4], aR1[j4*4+1], aR1[j4*4+2], aR1[j4*4+3]);
        }
    } else {
        // ---- Bucket role: edges rb*CHUNK .. +CHUNK ----
        unsigned short* srk  = (unsigned short*)smem;        // 16-bit rank, 0xFFFF=drop
        int* lcnt  = (int*)(smem + CHUNK * 2);               // NBKT counters
        int* fscan = lcnt + NBKT;                            // FD exclusive scan
        int* tscan = fscan + FD;                             // TB scratch

        for (int i = tid; i < NBKT; i += TB) lcnt[i] = 0;
        __syncthreads();

        int base = rb * CHUNK;
        float w0 = ws[0], w1 = ws[1];

        // pass A: mask + per-bucket rank (the count atomic's return IS the rank)
#pragma unroll
        for (int j = 0; j < CHUNK / TB; ++j) {
            int idx = j * TB + tid;
            int e = base + idx;
            unsigned short rk = 0xFFFFu;
            if (e < NE) {
                float ewm = w0 * As[e] + w1 * As[NE + e];
                if (ewm != 0.f)
                    rk = (unsigned short)atomicAdd(&lcnt[ei[NE + e] >> LB], 1); // <8192
            }
            srk[idx] = rk;
        }
        __syncthreads();

        // exclusive scan of 782 counters: thread t owns entries 2t, 2t+1
        {
            int loc[2]; int s = 0;
#pragma unroll
            for (int g = 0; g < 2; ++g) {
                int idx = tid * 2 + g;
                int v = (idx < NBKT) ? lcnt[idx] : 0;
                loc[g] = s; s += v;
            }
            tscan[tid] = s;
            __syncthreads();
            for (int off = 1; off < TB; off <<= 1) {
                int u = (tid >= off) ? tscan[tid - off] : 0;
                __syncthreads();
                tscan[tid] += u;
                __syncthreads();
            }
            int bse = (tid > 0) ? tscan[tid - 1] : 0;
#pragma unroll
            for (int g = 0; g < 2; ++g) {
                int idx = tid * 2 + g;
                if (idx < NBKT) fscan[idx] = bse + loc[g];
            }
            if (tid == TB - 1) fscan[NBKT] = tscan[TB - 1];
        }
        __syncthreads();

        // export directory row (coalesced)
        for (int i = tid; i < FD; i += TB)
            fdir[(size_t)rb * FD + i] = fscan[i];

        // pass B: re-read ei (L2-hot), place sorted into block-private region
#pragma unroll
        for (int j = 0; j < CHUNK / TB; ++j) {
            int idx = j * TB + tid;
            unsigned short rk = srk[idx];
            if (rk != 0xFFFFu) {
                int e   = base + idx;
                int dst = ei[NE + e];
                int bk  = dst >> LB;
                gchunk[(size_t)rb * CHUNK + fscan[bk] + rk] =
                    ((unsigned)ei[e] << LB) | (unsigned)(dst & (NPB - 1));
            }
        }
    }
}

// Layer-1 aggregation: gather this bucket's 196 fragments via the directory
// (read-side scatter, L2/L3-served), stage in LDS, counting-sort by dl, then
// 16-lane groups accumulate 8 nodes each in registers. dl-sorted list +
// offsets exported to bmem/gsoff for k_agg2.
// Fused epilogue: h = relu(acc + r + bl1); q = h.Wl2; out = h.Wr2 + bl2.
__global__ __launch_bounds__(256)
void k_agg1(const int* __restrict__ fdir, const unsigned int* __restrict__ gchunk,
            unsigned int* __restrict__ bmem,
            const unsigned short* __restrict__ p, const float* __restrict__ r,
            const float* __restrict__ bl1, const float* __restrict__ Wl2,
            const float* __restrict__ bl2, const float* __restrict__ Wr2,
            float* __restrict__ q, float* __restrict__ out,
            int* __restrict__ gsoff)
{
    __shared__ unsigned int sbm[CAP];       // 10 KB staged bucket
    __shared__ unsigned int ssorted[CAP];   // 10 KB sorted by dl
    __shared__ int fstart[NBF];             // fragment start in gchunk row
    __shared__ int foff[NBF + 1];           // exclusive scan of fragment sizes
    __shared__ int tscan[256];
    __shared__ int hist[NPB];
    __shared__ int hscan[NPB];
    __shared__ int soff[NPB + 1];

    int b = blockIdx.x;
    int tid = threadIdx.x;
    if (tid < NPB) hist[tid] = 0;

    // fragment directory: one fragment per thread (NBF=196 < 256)
    {
        int sz = 0;
        if (tid < NBF) {
            int s0 = fdir[(size_t)tid * FD + b];
            int s1 = fdir[(size_t)tid * FD + b + 1];
            fstart[tid] = s0;
            sz = s1 - s0;
        }
        tscan[tid] = sz;
        __syncthreads();
        for (int off = 1; off < 256; off <<= 1) {
            int u = (tid >= off) ? tscan[tid - off] : 0;
            __syncthreads();
            tscan[tid] += u;
            __syncthreads();
        }
        if (tid < NBF) foff[tid] = tscan[tid] - sz;   // exclusive
        if (tid == 255) foff[NBF] = tscan[255];
    }
    __syncthreads();

    int cnt = min(foff[NBF], CAP);

    // stage: 16-lane group per fragment; contiguous reads from gchunk
    {
        int grp = tid >> 4, k = tid & 15;
        for (int f = grp; f < NBF; f += 16) {
            int o  = foff[f];
            int sz = foff[f + 1] - o;
            int s  = fstart[f];
            const unsigned int* src = gchunk + (size_t)f * CHUNK + s;
            int lim = min(sz, CAP - o);
            for (int j = k; j < lim; j += 16)
                sbm[o + j] = src[j];
        }
    }
    __syncthreads();

    // histogram by dl; the atomic's return value is the rank
    int rk[CAP / 256];
#pragma unroll
    for (int j = 0; j < CAP / 256; ++j) {
        int i = j * 256 + tid;
        if (i < cnt)
            rk[j] = atomicAdd(&hist[sbm[i] & (NPB - 1)], 1);
    }
    __syncthreads();

    // exclusive scan of 128 counters
    if (tid < NPB) hscan[tid] = hist[tid];
    __syncthreads();
    for (int off = 1; off < NPB; off <<= 1) {
        int u = (tid < NPB && tid >= off) ? hscan[tid - off] : 0;
        __syncthreads();
        if (tid < NPB) hscan[tid] += u;
        __syncthreads();
    }
    if (tid < NPB) soff[tid + 1] = hscan[tid];
    if (tid == 0) soff[0] = 0;
    __syncthreads();

    // rank-scatter into ssorted
#pragma unroll
    for (int j = 0; j < CAP / 256; ++j) {
        int i = j * 256 + tid;
        if (i < cnt) {
            unsigned int w = sbm[i];
            ssorted[soff[w & (NPB - 1)] + rk[j]] = w;
        }
    }
    __syncthreads();

    // export sorted list (coalesced, line-aligned rows) + offsets for agg2
    for (int i = tid; i < cnt; i += 256)
        bmem[(size_t)b * CAP + i] = ssorted[i];
    if (tid < NPB + 1)
        gsoff[(size_t)b * (NPB + 1) + tid] = soff[tid];

    // register accumulation — group g owns nodes 8g..8g+7, lane k feature k
    int g = tid >> 4, k = tid & 15;
    int n0 = b * NPB;
#pragma unroll
    for (int jj = 0; jj < 8; ++jj) {
        int nl = g * 8 + jj;
        int s = soff[nl], e = soff[nl + 1];
        float a = 0.f;
        int i = s;
        for (; i + 3 < e; i += 4) {
            unsigned w0 = ssorted[i], w1 = ssorted[i+1], w2 = ssorted[i+2], w3 = ssorted[i+3];
            float v0 = bf16_to_f32(p[(size_t)(w0 >> LB) * NH + k]);
            float v1 = bf16_to_f32(p[(size_t)(w1 >> LB) * NH + k]);
            float v2 = bf16_to_f32(p[(size_t)(w2 >> LB) * NH + k]);
            float v3 = bf16_to_f32(p[(size_t)(w3 >> LB) * NH + k]);
            a += (v0 + v1) + (v2 + v3);
        }
        for (; i < e; ++i)
            a += bf16_to_f32(p[(size_t)(ssorted[i] >> LB) * NH + k]);

        int n = n0 + nl;
        if (n < NN) {
            float h = a + r[(size_t)n * NH + k] + bl1[k];
            h = h > 0.f ? h : 0.f;
            float qv = h * Wl2[k];
            float sv = h * Wr2[k];
#pragma unroll
            for (int m = 8; m >= 1; m >>= 1) {
                qv += __shfl_xor(qv, m);
                sv += __shfl_xor(sv, m);
            }
            if (k == 0) {
                q[n]   = qv;
                out[n] = sv + bl2[0];
            }
        }
    }
}

// Layer-2 aggregation: one thread per node scans its dl-sorted segment and
// gathers q[src] (400 KB, L2-resident).
__global__ __launch_bounds__(256)
void k_agg2(const int* __restrict__ gsoff, const unsigned int* __restrict__ bmem,
            const float* __restrict__ q, float* __restrict__ out)
{
    int n = blockIdx.x * 256 + threadIdx.x;
    if (n >= NN) return;
    int b  = n >> LB;
    int dl = n & (NPB - 1);
    int s = gsoff[(size_t)b * (NPB + 1) + dl];
    int e = gsoff[(size_t)b * (NPB + 1) + dl + 1];
    const unsigned int* bm = bmem + (size_t)b * CAP;

    float a = 0.f;
    int i = s;
    for (; i + 3 < e; i += 4) {
        unsigned w0 = bm[i], w1 = bm[i+1], w2 = bm[i+2], w3 = bm[i+3];
        a += (q[w0 >> LB] + q[w1 >> LB]) + (q[w2 >> LB] + q[w3 >> LB]);
    }
    for (; i < e; ++i)
        a += q[bm[i] >> LB];
    out[n] += a;
}

extern "C" void kernel_launch(void* const* d_in, const int* in_sizes, int n_in,
                              void* d_out, int out_size, void* d_ws, size_t ws_size,
                              hipStream_t stream)
{
    const float* x   = (const float*)d_in[0];
    const int*   ei  = (const int*)  d_in[1];
    const float* As  = (const float*)d_in[2];
    const float* ws  = (const float*)d_in[3];
    const float* Wl1 = (const float*)d_in[4];
    const float* bl1 = (const float*)d_in[5];
    const float* Wr1 = (const float*)d_in[6];
    const float* Wl2 = (const float*)d_in[7];
    const float* bl2 = (const float*)d_in[8];
    const float* Wr2 = (const float*)d_in[9];
    float* out = (float*)d_out;

    // workspace (~25 MB)
    unsigned short* p      = (unsigned short*)d_ws;            // NN*NH bf16 (3.2 MB)
    float*          r      = (float*)(p + (size_t)NN * NH);    // NN*NH f32 (6.4 MB)
    float*          q      = r + (size_t)NN * NH;              // NN
    int*            gsoff  = (int*)(q + NN);                   // NBKT*(NPB+1) (0.4 MB)
    int*            fdir   = gsoff + (size_t)NBKT * (NPB + 1); // NBF*FD (0.6 MB)
    unsigned int*   gchunk = (unsigned int*)(fdir + (size_t)NBF * FD); // NBF*CHUNK (6.4 MB)
    unsigned int*   bmem   = gchunk + (size_t)NBF * CHUNK;     // NBKT*CAP (8 MB)

    // 294 blocks: pattern [bucket, bucket, gemm] -> 196 bucket + 98 gemm
    k_fused<<<294, TB, 0, stream>>>(x, Wl1, Wr1, p, r, ei, As, ws, gchunk, fdir);
    k_agg1<<<NBKT, 256, 0, stream>>>(fdir, gchunk, bmem, p, r, bl1, Wl2, bl2, Wr2,
                                     q, out, gsoff);
    k_agg2<<<(NN + 255) / 256, 256, 0, stream>>>(gsoff, bmem, q, out);
}

// Round 13
// 172.594 us; speedup vs baseline: 3.7716x; 3.7716x over previous
//
#include <hip/hip_runtime.h>
#include <hip/hip_bf16.h>

constexpr int NN = 100000;   // nodes
constexpr int NE = 1600000;  // edges
constexpr int NF = 64;       // input features
constexpr int NH = 16;       // hidden

constexpr int NPB  = 128;                      // nodes per bucket (dst>>7 / dst&127)
constexpr int LB   = 7;                        // log2(NPB)
constexpr int NBKT = (NN + NPB - 1) / NPB;     // 782 buckets
constexpr int CAP  = 2560;                     // per-bucket edge capacity (mean 2046, +11 sigma)
constexpr int TB   = 512;                      // fused-kernel block size
constexpr int CHUNK = 8192;                    // edges per bucket-role block
constexpr int NBF   = (NE + CHUNK - 1) / CHUNK;   // 196 bucket-role blocks / fragments
constexpr int NBLK_K1 = (NN + TB - 1) / TB;       // 196 gemm-role blocks
constexpr int FD = NBKT + 1;                      // directory row stride (783)

// bucket-role LDS: srk 16K(u16) + lcnt 3.1K + fscan 3.1K + tscan 2K = 24.7 KB
constexpr int SMEM_BYTES = CHUNK * 2 + NBKT * 4 + FD * 4 + TB * 4;

__device__ __forceinline__ float bf16_to_f32(unsigned short u) {
    return __uint_as_float(((unsigned int)u) << 16);
}
__device__ __forceinline__ unsigned short f32_to_bf16(float f) {
    __hip_bfloat16 hb = __float2bfloat16(f);   // RNE
    return *reinterpret_cast<unsigned short*>(&hb);
}

// Fused front-end, 512 threads. Even blocks: p = bf16(x@Wl1), r = x@Wr1.
// Odd blocks: counting-sort an 8192-edge chunk by bucket; only a 16-bit rank
// lives in LDS (payload recomputed from L2-hot ei in pass B), keeping LDS at
// ~25 KB so occupancy is wave-capped, not LDS-capped.
// NOTE (R12 lesson): do NOT add per-thread accumulator arrays or float4
// weight indexing here — both spill (VGPR 56 -> 128, scratch traffic 670 MB).
__global__ __launch_bounds__(TB)
void k_fused(const float* __restrict__ x,
             const float* __restrict__ Wl1,
             const float* __restrict__ Wr1,
             unsigned short* __restrict__ p,
             float* __restrict__ r,
             const int* __restrict__ ei, const float* __restrict__ As,
             const float* __restrict__ ws,
             unsigned int* __restrict__ gchunk, int* __restrict__ fdir)
{
    __shared__ __align__(16) char smem[SMEM_BYTES];
    int role = blockIdx.x & 1;
    int rb   = blockIdx.x >> 1;
    int tid  = threadIdx.x;

    if (role == 0) {
        // ---- GEMM role: nodes rb*512 .. rb*512+511 ----
        float* sW = (float*)smem;
        for (int i = tid; i < NF * NH; i += TB) {
            sW[i]           = Wl1[i];
            sW[NF * NH + i] = Wr1[i];
        }
        __syncthreads();

        int n = rb * TB + tid;
        if (n >= NN) return;

        float aL[NH], aR[NH];
#pragma unroll
        for (int j = 0; j < NH; ++j) { aL[j] = 0.f; aR[j] = 0.f; }

        const float4* xr = reinterpret_cast<const float4*>(x + (size_t)n * NF);
#pragma unroll
        for (int k4 = 0; k4 < NF / 4; ++k4) {
            float4 v = xr[k4];
            float xs[4] = {v.x, v.y, v.z, v.w};
#pragma unroll
            for (int t2 = 0; t2 < 4; ++t2) {
                const float* wl = &sW[(k4 * 4 + t2) * NH];
                const float* wr = &sW[NF * NH + (k4 * 4 + t2) * NH];
#pragma unroll
                for (int j = 0; j < NH; ++j) {
                    aL[j] = fmaf(xs[t2], wl[j], aL[j]);
                    aR[j] = fmaf(xs[t2], wr[j], aR[j]);
                }
            }
        }

        unsigned int pu[8];
#pragma unroll
        for (int j2 = 0; j2 < 8; ++j2)
            pu[j2] = (unsigned int)f32_to_bf16(aL[2*j2]) |
                     ((unsigned int)f32_to_bf16(aL[2*j2+1]) << 16);
        uint4* pp = reinterpret_cast<uint4*>(p + (size_t)n * NH);
        pp[0] = make_uint4(pu[0], pu[1], pu[2], pu[3]);
        pp[1] = make_uint4(pu[4], pu[5], pu[6], pu[7]);

        float4* rp = reinterpret_cast<float4*>(r + (size_t)n * NH);
#pragma unroll
        for (int j4 = 0; j4 < NH / 4; ++j4)
            rp[j4] = make_float4(aR[j4*4], aR[j4*4+1], aR[j4*4+2], aR[j4*4+3]);
    } else {
        // ---- Bucket role: edges rb*CHUNK .. +CHUNK ----
        unsigned short* srk  = (unsigned short*)smem;        // 16-bit rank, 0xFFFF=drop
        int* lcnt  = (int*)(smem + CHUNK * 2);               // NBKT counters
        int* fscan = lcnt + NBKT;                            // FD exclusive scan
        int* tscan = fscan + FD;                             // TB scratch

        for (int i = tid; i < NBKT; i += TB) lcnt[i] = 0;
        __syncthreads();

        int base = rb * CHUNK;
        float w0 = ws[0], w1 = ws[1];

        // pass A: mask + per-bucket rank (the count atomic's return IS the rank)
#pragma unroll
        for (int j = 0; j < CHUNK / TB; ++j) {
            int idx = j * TB + tid;
            int e = base + idx;
            unsigned short rk = 0xFFFFu;
            if (e < NE) {
                float ewm = w0 * As[e] + w1 * As[NE + e];
                if (ewm != 0.f)
                    rk = (unsigned short)atomicAdd(&lcnt[ei[NE + e] >> LB], 1); // <8192
            }
            srk[idx] = rk;
        }
        __syncthreads();

        // exclusive scan of 782 counters: thread t owns entries 2t, 2t+1
        {
            int loc[2]; int s = 0;
#pragma unroll
            for (int g = 0; g < 2; ++g) {
                int idx = tid * 2 + g;
                int v = (idx < NBKT) ? lcnt[idx] : 0;
                loc[g] = s; s += v;
            }
            tscan[tid] = s;
            __syncthreads();
            for (int off = 1; off < TB; off <<= 1) {
                int u = (tid >= off) ? tscan[tid - off] : 0;
                __syncthreads();
                tscan[tid] += u;
                __syncthreads();
            }
            int bse = (tid > 0) ? tscan[tid - 1] : 0;
#pragma unroll
            for (int g = 0; g < 2; ++g) {
                int idx = tid * 2 + g;
                if (idx < NBKT) fscan[idx] = bse + loc[g];
            }
            if (tid == TB - 1) fscan[NBKT] = tscan[TB - 1];
        }
        __syncthreads();

        // export directory row (coalesced)
        for (int i = tid; i < FD; i += TB)
            fdir[(size_t)rb * FD + i] = fscan[i];

        // pass B: re-read ei (dst half L2-hot), place sorted into the
        // block-private region (dense, line-clean writes)
#pragma unroll
        for (int j = 0; j < CHUNK / TB; ++j) {
            int idx = j * TB + tid;
            unsigned short rk = srk[idx];
            if (rk != 0xFFFFu) {
                int e   = base + idx;
                int dst = ei[NE + e];
                int bk  = dst >> LB;
                gchunk[(size_t)rb * CHUNK + fscan[bk] + rk] =
                    ((unsigned)ei[e] << LB) | (unsigned)(dst & (NPB - 1));
            }
        }
    }
}

// Layer-1 aggregation: gather this bucket's 196 fragments via the directory
// (read-side scatter, L2/L3-served), stage in LDS, counting-sort by dl, then
// 16-lane groups accumulate 8 nodes each in registers. dl-sorted list +
// offsets exported to bmem/gsoff for k_agg2.
// Fused epilogue: h = relu(acc + r + bl1); q = h.Wl2; out = h.Wr2 + bl2.
__global__ __launch_bounds__(256)
void k_agg1(const int* __restrict__ fdir, const unsigned int* __restrict__ gchunk,
            unsigned int* __restrict__ bmem,
            const unsigned short* __restrict__ p, const float* __restrict__ r,
            const float* __restrict__ bl1, const float* __restrict__ Wl2,
            const float* __restrict__ bl2, const float* __restrict__ Wr2,
            float* __restrict__ q, float* __restrict__ out,
            int* __restrict__ gsoff)
{
    __shared__ unsigned int sbm[CAP];       // 10 KB staged bucket
    __shared__ unsigned int ssorted[CAP];   // 10 KB sorted by dl
    __shared__ int fstart[NBF];             // fragment start in gchunk row
    __shared__ int foff[NBF + 1];           // exclusive scan of fragment sizes
    __shared__ int tscan[256];
    __shared__ int hist[NPB];
    __shared__ int hscan[NPB];
    __shared__ int soff[NPB + 1];

    int b = blockIdx.x;
    int tid = threadIdx.x;
    if (tid < NPB) hist[tid] = 0;

    // fragment directory: one fragment per thread (NBF=196 < 256)
    {
        int sz = 0;
        if (tid < NBF) {
            int s0 = fdir[(size_t)tid * FD + b];
            int s1 = fdir[(size_t)tid * FD + b + 1];
            fstart[tid] = s0;
            sz = s1 - s0;
        }
        tscan[tid] = sz;
        __syncthreads();
        for (int off = 1; off < 256; off <<= 1) {
            int u = (tid >= off) ? tscan[tid - off] : 0;
            __syncthreads();
            tscan[tid] += u;
            __syncthreads();
        }
        if (tid < NBF) foff[tid] = tscan[tid] - sz;   // exclusive
        if (tid == 255) foff[NBF] = tscan[255];
    }
    __syncthreads();

    int cnt = min(foff[NBF], CAP);

    // stage: 16-lane group per fragment; contiguous reads from gchunk
    {
        int grp = tid >> 4, k = tid & 15;
        for (int f = grp; f < NBF; f += 16) {
            int o  = foff[f];
            int sz = foff[f + 1] - o;
            int s  = fstart[f];
            const unsigned int* src = gchunk + (size_t)f * CHUNK + s;
            int lim = min(sz, CAP - o);
            for (int j = k; j < lim; j += 16)
                sbm[o + j] = src[j];
        }
    }
    __syncthreads();

    // histogram by dl; the atomic's return value is the rank
    int rk[CAP / 256];
#pragma unroll
    for (int j = 0; j < CAP / 256; ++j) {
        int i = j * 256 + tid;
        if (i < cnt)
            rk[j] = atomicAdd(&hist[sbm[i] & (NPB - 1)], 1);
    }
    __syncthreads();

    // exclusive scan of 128 counters
    if (tid < NPB) hscan[tid] = hist[tid];
    __syncthreads();
    for (int off = 1; off < NPB; off <<= 1) {
        int u = (tid < NPB && tid >= off) ? hscan[tid - off] : 0;
        __syncthreads();
        if (tid < NPB) hscan[tid] += u;
        __syncthreads();
    }
    if (tid < NPB) soff[tid + 1] = hscan[tid];
    if (tid == 0) soff[0] = 0;
    __syncthreads();

    // rank-scatter into ssorted
#pragma unroll
    for (int j = 0; j < CAP / 256; ++j) {
        int i = j * 256 + tid;
        if (i < cnt) {
            unsigned int w = sbm[i];
            ssorted[soff[w & (NPB - 1)] + rk[j]] = w;
        }
    }
    __syncthreads();

    // export sorted list (coalesced, line-aligned rows) + offsets for agg2
    for (int i = tid; i < cnt; i += 256)
        bmem[(size_t)b * CAP + i] = ssorted[i];
    if (tid < NPB + 1)
        gsoff[(size_t)b * (NPB + 1) + tid] = soff[tid];

    // register accumulation — group g owns nodes 8g..8g+7, lane k feature k
    int g = tid >> 4, k = tid & 15;
    int n0 = b * NPB;
#pragma unroll
    for (int jj = 0; jj < 8; ++jj) {
        int nl = g * 8 + jj;
        int s = soff[nl], e = soff[nl + 1];
        float a = 0.f;
        int i = s;
        for (; i + 3 < e; i += 4) {
            unsigned w0 = ssorted[i], w1 = ssorted[i+1], w2 = ssorted[i+2], w3 = ssorted[i+3];
            float v0 = bf16_to_f32(p[(size_t)(w0 >> LB) * NH + k]);
            float v1 = bf16_to_f32(p[(size_t)(w1 >> LB) * NH + k]);
            float v2 = bf16_to_f32(p[(size_t)(w2 >> LB) * NH + k]);
            float v3 = bf16_to_f32(p[(size_t)(w3 >> LB) * NH + k]);
            a += (v0 + v1) + (v2 + v3);
        }
        for (; i < e; ++i)
            a += bf16_to_f32(p[(size_t)(ssorted[i] >> LB) * NH + k]);

        int n = n0 + nl;
        if (n < NN) {
            float h = a + r[(size_t)n * NH + k] + bl1[k];
            h = h > 0.f ? h : 0.f;
            float qv = h * Wl2[k];
            float sv = h * Wr2[k];
#pragma unroll
            for (int m = 8; m >= 1; m >>= 1) {
                qv += __shfl_xor(qv, m);
                sv += __shfl_xor(sv, m);
            }
            if (k == 0) {
                q[n]   = qv;
                out[n] = sv + bl2[0];
            }
        }
    }
}

// Layer-2 aggregation: one thread per node scans its dl-sorted segment and
// gathers q[src] (400 KB, L2-resident).
__global__ __launch_bounds__(256)
void k_agg2(const int* __restrict__ gsoff, const unsigned int* __restrict__ bmem,
            const float* __restrict__ q, float* __restrict__ out)
{
    int n = blockIdx.x * 256 + threadIdx.x;
    if (n >= NN) return;
    int b  = n >> LB;
    int dl = n & (NPB - 1);
    int s = gsoff[(size_t)b * (NPB + 1) + dl];
    int e = gsoff[(size_t)b * (NPB + 1) + dl + 1];
    const unsigned int* bm = bmem + (size_t)b * CAP;

    float a = 0.f;
    int i = s;
    for (; i + 3 < e; i += 4) {
        unsigned w0 = bm[i], w1 = bm[i+1], w2 = bm[i+2], w3 = bm[i+3];
        a += (q[w0 >> LB] + q[w1 >> LB]) + (q[w2 >> LB] + q[w3 >> LB]);
    }
    for (; i < e; ++i)
        a += q[bm[i] >> LB];
    out[n] += a;
}

extern "C" void kernel_launch(void* const* d_in, const int* in_sizes, int n_in,
                              void* d_out, int out_size, void* d_ws, size_t ws_size,
                              hipStream_t stream)
{
    const float* x   = (const float*)d_in[0];
    const int*   ei  = (const int*)  d_in[1];
    const float* As  = (const float*)d_in[2];
    const float* ws  = (const float*)d_in[3];
    const float* Wl1 = (const float*)d_in[4];
    const float* bl1 = (const float*)d_in[5];
    const float* Wr1 = (const float*)d_in[6];
    const float* Wl2 = (const float*)d_in[7];
    const float* bl2 = (const float*)d_in[8];
    const float* Wr2 = (const float*)d_in[9];
    float* out = (float*)d_out;

    // workspace (~25 MB)
    unsigned short* p      = (unsigned short*)d_ws;            // NN*NH bf16 (3.2 MB)
    float*          r      = (float*)(p + (size_t)NN * NH);    // NN*NH f32 (6.4 MB)
    float*          q      = r + (size_t)NN * NH;              // NN
    int*            gsoff  = (int*)(q + NN);                   // NBKT*(NPB+1) (0.4 MB)
    int*            fdir   = gsoff + (size_t)NBKT * (NPB + 1); // NBF*FD (0.6 MB)
    unsigned int*   gchunk = (unsigned int*)(fdir + (size_t)NBF * FD); // NBF*CHUNK (6.4 MB)
    unsigned int*   bmem   = gchunk + (size_t)NBF * CHUNK;     // NBKT*CAP (8 MB)

    int nblk = 2 * ((NBF > NBLK_K1) ? NBF : NBLK_K1);          // 392, roles interleaved
    k_fused<<<nblk, TB, 0, stream>>>(x, Wl1, Wr1, p, r, ei, As, ws, gchunk, fdir);
    k_agg1<<<NBKT, 256, 0, stream>>>(fdir, gchunk, bmem, p, r, bl1, Wl2, bl2, Wr2,
                                     q, out, gsoff);
    k_agg2<<<(NN + 255) / 256, 256, 0, stream>>>(gsoff, bmem, q, out);
}